// Round 1
// baseline (8772.598 us; speedup 1.0000x reference)
//
#include <hip/hip_runtime.h>

#define NU 100000
#define NI 100000
#define NE 500000
#define HD 128

// ---------------- degree histograms (6 arrays of 100000) ----------------
__global__ __launch_bounds__(256) void deg_count(
    const int* __restrict__ i0, const int* __restrict__ i1,
    const int* __restrict__ i2, const int* __restrict__ i3,
    const int* __restrict__ i4, const int* __restrict__ i5,
    float* __restrict__ deg)
{
    long long t = (long long)blockIdx.x * 256 + threadIdx.x;
    if (t >= 6LL * NE) return;
    int a = (int)(t / NE);
    int e = (int)(t - (long long)a * NE);
    const int* p = (a == 0) ? i0 : (a == 1) ? i1 : (a == 2) ? i2
                 : (a == 3) ? i3 : (a == 4) ? i4 : i5;
    atomicAdd(&deg[a * 100000 + p[e]], 1.0f);
}

__global__ __launch_bounds__(256) void deg_finalize(float* __restrict__ deg)
{
    int t = blockIdx.x * 256 + threadIdx.x;
    if (t < 600000) deg[t] = rsqrtf(fmaxf(deg[t], 1.0f));
}

// ---------------- edge scatter: m[dst] += x[src] * rs_out[src] ----------------
__global__ __launch_bounds__(256) void scatter_scaled(
    const float* __restrict__ x, const float* __restrict__ rs,
    const int* __restrict__ src, const int* __restrict__ dst,
    float* __restrict__ m)
{
    long long t = (long long)blockIdx.x * 256 + threadIdx.x;
    if (t >= (long long)NE * 32) return;
    int e = (int)(t >> 5);
    int c = ((int)t & 31) * 4;
    int s = src[e], d = dst[e];
    float sc = rs[s];
    const float4 v = *(const float4*)(x + (long long)s * HD + c);
    float* mp = m + (long long)d * HD + c;
    atomicAdd(mp + 0, v.x * sc);
    atomicAdd(mp + 1, v.y * sc);
    atomicAdd(mp + 2, v.z * sc);
    atomicAdd(mp + 3, v.w * sc);
}

// ---------------- C[M x 128] = A[M x K] @ W[K x 128], fused epilogue ----------------
// epilogue: o = acc * out_scale[row] + bias; relu; optional += existing C
__global__ __launch_bounds__(256) void gemm128(
    const float* __restrict__ A, int K, int M,
    const float* __restrict__ W,
    const float* __restrict__ bias,
    const float* __restrict__ out_scale,
    int do_relu, int do_accum,
    float* __restrict__ C)
{
    __shared__ float sA[64 * 32];
    __shared__ float sW[32 * 128];
    const int tid = threadIdx.x;
    const int row0 = blockIdx.x * 64;
    const int tx = tid & 31;   // col group: cols tx*4 .. tx*4+3
    const int ty = tid >> 5;   // row group: rows ty*8 .. ty*8+7

    float acc[8][4];
#pragma unroll
    for (int r = 0; r < 8; ++r)
#pragma unroll
        for (int j = 0; j < 4; ++j) acc[r][j] = 0.f;

    const int nk = (K + 31) >> 5;
    for (int kc = 0; kc < nk; ++kc) {
        const int k0 = kc << 5;
        // stage A tile: 64 rows x 32 k (2 float4 per thread)
#pragma unroll
        for (int i = 0; i < 2; ++i) {
            int id = tid + i * 256;
            int lr = id >> 3;
            int kq = (id & 7) << 2;
            int row = row0 + lr;
            int k = k0 + kq;
            float4 v = make_float4(0.f, 0.f, 0.f, 0.f);
            if (row < M) {
                if (k + 3 < K) {
                    v = *(const float4*)(A + (long long)row * K + k);
                } else {
                    float q0 = (k + 0 < K) ? A[(long long)row * K + k + 0] : 0.f;
                    float q1 = (k + 1 < K) ? A[(long long)row * K + k + 1] : 0.f;
                    float q2 = (k + 2 < K) ? A[(long long)row * K + k + 2] : 0.f;
                    float q3 = (k + 3 < K) ? A[(long long)row * K + k + 3] : 0.f;
                    v = make_float4(q0, q1, q2, q3);
                }
            }
            *(float4*)(sA + lr * 32 + kq) = v;
        }
        // stage W tile: 32 k x 128 cols (4 float4 per thread)
#pragma unroll
        for (int j = 0; j < 4; ++j) {
            int krow = ty + j * 8;
            int k = k0 + krow;
            float4 v = make_float4(0.f, 0.f, 0.f, 0.f);
            if (k < K) v = *(const float4*)(W + (long long)k * 128 + tx * 4);
            *(float4*)(sW + krow * 128 + tx * 4) = v;
        }
        __syncthreads();
#pragma unroll
        for (int kq = 0; kq < 8; ++kq) {
            float wf[4][4];
#pragma unroll
            for (int j = 0; j < 4; ++j) {
                float4 wv = *(const float4*)(sW + (kq * 4 + j) * 128 + tx * 4);
                wf[j][0] = wv.x; wf[j][1] = wv.y; wf[j][2] = wv.z; wf[j][3] = wv.w;
            }
#pragma unroll
            for (int r = 0; r < 8; ++r) {
                float4 av = *(const float4*)(sA + (ty * 8 + r) * 32 + kq * 4);
                float af[4] = {av.x, av.y, av.z, av.w};
#pragma unroll
                for (int kk = 0; kk < 4; ++kk)
#pragma unroll
                    for (int j = 0; j < 4; ++j)
                        acc[r][j] = fmaf(af[kk], wf[kk][j], acc[r][j]);
            }
        }
        __syncthreads();
    }

    float bv[4] = {0.f, 0.f, 0.f, 0.f};
    if (bias) {
        float4 b = *(const float4*)(bias + tx * 4);
        bv[0] = b.x; bv[1] = b.y; bv[2] = b.z; bv[3] = b.w;
    }
#pragma unroll
    for (int r = 0; r < 8; ++r) {
        int row = row0 + ty * 8 + r;
        if (row < M) {
            float s = out_scale ? out_scale[row] : 1.f;
            float o[4];
#pragma unroll
            for (int j = 0; j < 4; ++j) {
                float v = acc[r][j] * s + bv[j];
                if (do_relu) v = fmaxf(v, 0.f);
                o[j] = v;
            }
            float* cp = C + (long long)row * 128 + tx * 4;
            if (do_accum) {
                float4 prev = *(const float4*)cp;
                o[0] += prev.x; o[1] += prev.y; o[2] += prev.z; o[3] += prev.w;
            }
            *(float4*)cp = make_float4(o[0], o[1], o[2], o[3]);
        }
    }
}

extern "C" void kernel_launch(void* const* d_in, const int* in_sizes, int n_in,
                              void* d_out, int out_size, void* d_ws, size_t ws_size,
                              hipStream_t stream)
{
    const float* feat_user = (const float*)d_in[0];
    const float* feat_item = (const float*)d_in[1];
    const int* src_uu = (const int*)d_in[2];
    const int* dst_uu = (const int*)d_in[3];
    const int* src_ui = (const int*)d_in[4];
    const int* dst_ui = (const int*)d_in[5];
    const int* src_iu = (const int*)d_in[6];
    const int* dst_iu = (const int*)d_in[7];
    const float* We_u = (const float*)d_in[8];
    const float* be_u = (const float*)d_in[9];
    const float* We_i = (const float*)d_in[10];
    const float* be_i = (const float*)d_in[11];

    float* hu = (float*)d_out;                 // [NU x 128]
    float* hi = hu + (size_t)NU * HD;          // [NI x 128]

    float* ws   = (float*)d_ws;
    float* m_uu = ws;                          // [NU x 128] dst=user
    float* m_ui = m_uu + (size_t)NU * HD;      // [NI x 128] dst=item
    float* m_iu = m_ui + (size_t)NI * HD;      // [NU x 128] dst=user
    float* deg  = m_iu + (size_t)NU * HD;      // 6 x 100000
    float* rs_out_uu = deg + 0;
    float* rs_in_uu  = deg + 100000;
    float* rs_out_ui = deg + 200000;
    float* rs_in_ui  = deg + 300000;
    float* rs_out_iu = deg + 400000;
    float* rs_in_iu  = deg + 500000;

    // degrees (once; graph shared across layers)
    hipMemsetAsync(deg, 0, 600000 * sizeof(float), stream);
    deg_count<<<(6 * NE + 255) / 256, 256, 0, stream>>>(
        src_uu, dst_uu, src_ui, dst_ui, src_iu, dst_iu, deg);
    deg_finalize<<<(600000 + 255) / 256, 256, 0, stream>>>(deg);

    // HeteroLinear embed
    gemm128<<<(NU + 63) / 64, 256, 0, stream>>>(feat_user, 256, NU, We_u, be_u,
                                                nullptr, 0, 0, hu);
    gemm128<<<(NI + 63) / 64, 256, 0, stream>>>(feat_item, 300, NI, We_i, be_i,
                                                nullptr, 0, 0, hi);

    const int scat_blocks = (int)(((long long)NE * 32 + 255) / 256);
    for (int l = 0; l < 3; ++l) {
        const float* W_uu = (const float*)d_in[12 + 6 * l + 0];
        const float* b_uu = (const float*)d_in[12 + 6 * l + 1];
        const float* W_ui = (const float*)d_in[12 + 6 * l + 2];
        const float* b_ui = (const float*)d_in[12 + 6 * l + 3];
        const float* W_iu = (const float*)d_in[12 + 6 * l + 4];
        const float* b_iu = (const float*)d_in[12 + 6 * l + 5];
        const int relu = (l < 2) ? 1 : 0;

        hipMemsetAsync(m_uu, 0, 3 * (size_t)NU * HD * sizeof(float), stream);
        // aggregate-first: m = segment_sum((x * rsqrt(deg_out))[src], dst)
        scatter_scaled<<<scat_blocks, 256, 0, stream>>>(hu, rs_out_uu, src_uu, dst_uu, m_uu);
        scatter_scaled<<<scat_blocks, 256, 0, stream>>>(hu, rs_out_ui, src_ui, dst_ui, m_ui);
        scatter_scaled<<<scat_blocks, 256, 0, stream>>>(hi, rs_out_iu, src_iu, dst_iu, m_iu);
        // then GEMM with fused epilogue: relu((m @ W) * rsqrt(deg_in) + b), summed per dst ntype
        gemm128<<<(NU + 63) / 64, 256, 0, stream>>>(m_uu, HD, NU, W_uu, b_uu, rs_in_uu, relu, 0, hu);
        gemm128<<<(NU + 63) / 64, 256, 0, stream>>>(m_iu, HD, NU, W_iu, b_iu, rs_in_iu, relu, 1, hu);
        gemm128<<<(NI + 63) / 64, 256, 0, stream>>>(m_ui, HD, NI, W_ui, b_ui, rs_in_ui, relu, 0, hi);
    }
}

// Round 2
// 1749.545 us; speedup vs baseline: 5.0142x; 5.0142x over previous
//
#include <hip/hip_runtime.h>

#define NU 100000
#define NI 100000
#define NE 500000
#define HD 128

// ---------------- degree histograms (6 arrays of 100000) ----------------
__global__ __launch_bounds__(256) void deg_count(
    const int* __restrict__ i0, const int* __restrict__ i1,
    const int* __restrict__ i2, const int* __restrict__ i3,
    const int* __restrict__ i4, const int* __restrict__ i5,
    float* __restrict__ deg)
{
    long long t = (long long)blockIdx.x * 256 + threadIdx.x;
    if (t >= 6LL * NE) return;
    int a = (int)(t / NE);
    int e = (int)(t - (long long)a * NE);
    const int* p = (a == 0) ? i0 : (a == 1) ? i1 : (a == 2) ? i2
                 : (a == 3) ? i3 : (a == 4) ? i4 : i5;
    atomicAdd(&deg[a * 100000 + p[e]], 1.0f);
}

__global__ __launch_bounds__(256) void deg_finalize(float* __restrict__ deg)
{
    int t = blockIdx.x * 256 + threadIdx.x;
    if (t < 600000) deg[t] = rsqrtf(fmaxf(deg[t], 1.0f));
}

// ---------------- CSR build ----------------
__global__ __launch_bounds__(256) void count_dst(const int* __restrict__ dst,
                                                 int* __restrict__ cnt)
{
    int e = blockIdx.x * 256 + threadIdx.x;
    if (e < NE) atomicAdd(&cnt[dst[e]], 1);
}

// phase 1: per-block exclusive scan, block totals
__global__ __launch_bounds__(256) void scan_block(const int* __restrict__ cnt, int n,
                                                  int* __restrict__ rp,
                                                  int* __restrict__ bsum)
{
    __shared__ int s[256];
    int gid = blockIdx.x * 256 + threadIdx.x;
    int v = (gid < n) ? cnt[gid] : 0;
    s[threadIdx.x] = v;
    __syncthreads();
#pragma unroll
    for (int off = 1; off < 256; off <<= 1) {
        int t = (threadIdx.x >= off) ? s[threadIdx.x - off] : 0;
        __syncthreads();
        s[threadIdx.x] += t;
        __syncthreads();
    }
    if (gid < n) rp[gid] = s[threadIdx.x] - v;   // exclusive
    if (threadIdx.x == 255) bsum[blockIdx.x] = s[255];
}

// phase 2: single-block exclusive scan of block sums (nb <= 512), append total
__global__ __launch_bounds__(512) void scan_bsums(int* __restrict__ bsum, int nb)
{
    __shared__ int s[512];
    int v = (threadIdx.x < nb) ? bsum[threadIdx.x] : 0;
    s[threadIdx.x] = v;
    __syncthreads();
#pragma unroll
    for (int off = 1; off < 512; off <<= 1) {
        int t = (threadIdx.x >= off) ? s[threadIdx.x - off] : 0;
        __syncthreads();
        s[threadIdx.x] += t;
        __syncthreads();
    }
    if (threadIdx.x < nb) bsum[threadIdx.x] = s[threadIdx.x] - v;
    if (threadIdx.x == 0) bsum[nb] = s[nb - 1];  // total
}

// phase 3: add block offsets; write rp[n]
__global__ __launch_bounds__(256) void scan_add(int* __restrict__ rp,
                                                const int* __restrict__ bsum,
                                                int n, int nb)
{
    int gid = blockIdx.x * 256 + threadIdx.x;
    if (gid < n) rp[gid] += bsum[blockIdx.x];
    if (gid == 0) rp[n] = bsum[nb];
}

__global__ __launch_bounds__(256) void csr_fill(const int* __restrict__ src,
                                                const int* __restrict__ dst,
                                                const int* __restrict__ rp,
                                                int* __restrict__ cursor,
                                                int* __restrict__ eidx)
{
    int e = blockIdx.x * 256 + threadIdx.x;
    if (e >= NE) return;
    int d = dst[e];
    int pos = rp[d] + atomicAdd(&cursor[d], 1);
    eidx[pos] = src[e];
}

// ---------------- CSR gather: m[d] = sum_{e in csr[d]} x[src_e] * rs[src_e] ----------------
__global__ __launch_bounds__(256) void gather_scaled(
    const float* __restrict__ x, const float* __restrict__ rs,
    const int* __restrict__ rp, const int* __restrict__ eidx,
    float* __restrict__ m, int n)
{
    int row = blockIdx.x * 8 + (threadIdx.x >> 5);
    int c = (threadIdx.x & 31) * 4;
    if (row >= n) return;
    int beg = rp[row], end = rp[row + 1];
    float ax = 0.f, ay = 0.f, az = 0.f, aw = 0.f;
    for (int p = beg; p < end; ++p) {
        int s = eidx[p];
        float sc = rs[s];
        float4 v = *(const float4*)(x + (long long)s * HD + c);
        ax = fmaf(v.x, sc, ax);
        ay = fmaf(v.y, sc, ay);
        az = fmaf(v.z, sc, az);
        aw = fmaf(v.w, sc, aw);
    }
    *(float4*)(m + (long long)row * HD + c) = make_float4(ax, ay, az, aw);
}

// ---------------- C[M x 128] = A[M x K] @ W[K x 128], fused epilogue ----------------
__global__ __launch_bounds__(256) void gemm128(
    const float* __restrict__ A, int K, int M,
    const float* __restrict__ W,
    const float* __restrict__ bias,
    const float* __restrict__ out_scale,
    int do_relu, int do_accum,
    float* __restrict__ C)
{
    __shared__ float sA[64 * 32];
    __shared__ float sW[32 * 128];
    const int tid = threadIdx.x;
    const int row0 = blockIdx.x * 64;
    const int tx = tid & 31;
    const int ty = tid >> 5;

    float acc[8][4];
#pragma unroll
    for (int r = 0; r < 8; ++r)
#pragma unroll
        for (int j = 0; j < 4; ++j) acc[r][j] = 0.f;

    const int nk = (K + 31) >> 5;
    for (int kc = 0; kc < nk; ++kc) {
        const int k0 = kc << 5;
#pragma unroll
        for (int i = 0; i < 2; ++i) {
            int id = tid + i * 256;
            int lr = id >> 3;
            int kq = (id & 7) << 2;
            int row = row0 + lr;
            int k = k0 + kq;
            float4 v = make_float4(0.f, 0.f, 0.f, 0.f);
            if (row < M) {
                if (k + 3 < K) {
                    v = *(const float4*)(A + (long long)row * K + k);
                } else {
                    float q0 = (k + 0 < K) ? A[(long long)row * K + k + 0] : 0.f;
                    float q1 = (k + 1 < K) ? A[(long long)row * K + k + 1] : 0.f;
                    float q2 = (k + 2 < K) ? A[(long long)row * K + k + 2] : 0.f;
                    float q3 = (k + 3 < K) ? A[(long long)row * K + k + 3] : 0.f;
                    v = make_float4(q0, q1, q2, q3);
                }
            }
            *(float4*)(sA + lr * 32 + kq) = v;
        }
#pragma unroll
        for (int j = 0; j < 4; ++j) {
            int krow = ty + j * 8;
            int k = k0 + krow;
            float4 v = make_float4(0.f, 0.f, 0.f, 0.f);
            if (k < K) v = *(const float4*)(W + (long long)k * 128 + tx * 4);
            *(float4*)(sW + krow * 128 + tx * 4) = v;
        }
        __syncthreads();
#pragma unroll
        for (int kq = 0; kq < 8; ++kq) {
            float wf[4][4];
#pragma unroll
            for (int j = 0; j < 4; ++j) {
                float4 wv = *(const float4*)(sW + (kq * 4 + j) * 128 + tx * 4);
                wf[j][0] = wv.x; wf[j][1] = wv.y; wf[j][2] = wv.z; wf[j][3] = wv.w;
            }
#pragma unroll
            for (int r = 0; r < 8; ++r) {
                float4 av = *(const float4*)(sA + (ty * 8 + r) * 32 + kq * 4);
                float af[4] = {av.x, av.y, av.z, av.w};
#pragma unroll
                for (int kk = 0; kk < 4; ++kk)
#pragma unroll
                    for (int j = 0; j < 4; ++j)
                        acc[r][j] = fmaf(af[kk], wf[kk][j], acc[r][j]);
            }
        }
        __syncthreads();
    }

    float bv[4] = {0.f, 0.f, 0.f, 0.f};
    if (bias) {
        float4 b = *(const float4*)(bias + tx * 4);
        bv[0] = b.x; bv[1] = b.y; bv[2] = b.z; bv[3] = b.w;
    }
#pragma unroll
    for (int r = 0; r < 8; ++r) {
        int row = row0 + ty * 8 + r;
        if (row < M) {
            float s = out_scale ? out_scale[row] : 1.f;
            float o[4];
#pragma unroll
            for (int j = 0; j < 4; ++j) {
                float v = acc[r][j] * s + bv[j];
                if (do_relu) v = fmaxf(v, 0.f);
                o[j] = v;
            }
            float* cp = C + (long long)row * 128 + tx * 4;
            if (do_accum) {
                float4 prev = *(const float4*)cp;
                o[0] += prev.x; o[1] += prev.y; o[2] += prev.z; o[3] += prev.w;
            }
            *(float4*)cp = make_float4(o[0], o[1], o[2], o[3]);
        }
    }
}

static inline void build_csr(const int* src, const int* dst, int n_dst,
                             int* cnt, int* rp, int* cursor, int* eidx,
                             int* bsum, hipStream_t stream)
{
    const int nb = (n_dst + 255) / 256;
    hipMemsetAsync(cnt, 0, n_dst * sizeof(int), stream);
    count_dst<<<(NE + 255) / 256, 256, 0, stream>>>(dst, cnt);
    scan_block<<<nb, 256, 0, stream>>>(cnt, n_dst, rp, bsum);
    scan_bsums<<<1, 512, 0, stream>>>(bsum, nb);
    scan_add<<<nb, 256, 0, stream>>>(rp, bsum, n_dst, nb);
    hipMemsetAsync(cursor, 0, n_dst * sizeof(int), stream);
    csr_fill<<<(NE + 255) / 256, 256, 0, stream>>>(src, dst, rp, cursor, eidx);
}

extern "C" void kernel_launch(void* const* d_in, const int* in_sizes, int n_in,
                              void* d_out, int out_size, void* d_ws, size_t ws_size,
                              hipStream_t stream)
{
    const float* feat_user = (const float*)d_in[0];
    const float* feat_item = (const float*)d_in[1];
    const int* src_uu = (const int*)d_in[2];
    const int* dst_uu = (const int*)d_in[3];
    const int* src_ui = (const int*)d_in[4];
    const int* dst_ui = (const int*)d_in[5];
    const int* src_iu = (const int*)d_in[6];
    const int* dst_iu = (const int*)d_in[7];
    const float* We_u = (const float*)d_in[8];
    const float* be_u = (const float*)d_in[9];
    const float* We_i = (const float*)d_in[10];
    const float* be_i = (const float*)d_in[11];

    float* hu = (float*)d_out;                 // [NU x 128]
    float* hi = hu + (size_t)NU * HD;          // [NI x 128]

    float* ws   = (float*)d_ws;
    float* m_uu = ws;                          // [NU x 128] dst=user
    float* m_ui = m_uu + (size_t)NU * HD;      // [NI x 128] dst=item
    float* m_iu = m_ui + (size_t)NI * HD;      // [NU x 128] dst=user
    float* deg  = m_iu + (size_t)NU * HD;      // 6 x 100000
    float* rs_out_uu = deg + 0;
    float* rs_in_uu  = deg + 100000;
    float* rs_out_ui = deg + 200000;
    float* rs_in_ui  = deg + 300000;
    float* rs_out_iu = deg + 400000;
    float* rs_in_iu  = deg + 500000;

    int* ib = (int*)(deg + 600000);
    int* rp_uu   = ib;                 ib += 100001;
    int* rp_ui   = ib;                 ib += 100001;
    int* rp_iu   = ib;                 ib += 100001;
    int* ei_uu   = ib;                 ib += NE;
    int* ei_ui   = ib;                 ib += NE;
    int* ei_iu   = ib;                 ib += NE;
    int* cnt     = ib;                 ib += 100000;
    int* cursor  = ib;                 ib += 100000;
    int* bsum    = ib;                 ib += 1024;

    // degrees (once; graph shared across layers)
    hipMemsetAsync(deg, 0, 600000 * sizeof(float), stream);
    deg_count<<<(6 * NE + 255) / 256, 256, 0, stream>>>(
        src_uu, dst_uu, src_ui, dst_ui, src_iu, dst_iu, deg);
    deg_finalize<<<(600000 + 255) / 256, 256, 0, stream>>>(deg);

    // CSR (dst-major) per etype, built once
    build_csr(src_uu, dst_uu, NU, cnt, rp_uu, cursor, ei_uu, bsum, stream);
    build_csr(src_ui, dst_ui, NI, cnt, rp_ui, cursor, ei_ui, bsum, stream);
    build_csr(src_iu, dst_iu, NU, cnt, rp_iu, cursor, ei_iu, bsum, stream);

    // HeteroLinear embed
    gemm128<<<(NU + 63) / 64, 256, 0, stream>>>(feat_user, 256, NU, We_u, be_u,
                                                nullptr, 0, 0, hu);
    gemm128<<<(NI + 63) / 64, 256, 0, stream>>>(feat_item, 300, NI, We_i, be_i,
                                                nullptr, 0, 0, hi);

    const int gat_blocks_u = (NU + 7) / 8;
    const int gat_blocks_i = (NI + 7) / 8;
    for (int l = 0; l < 3; ++l) {
        const float* W_uu = (const float*)d_in[12 + 6 * l + 0];
        const float* b_uu = (const float*)d_in[12 + 6 * l + 1];
        const float* W_ui = (const float*)d_in[12 + 6 * l + 2];
        const float* b_ui = (const float*)d_in[12 + 6 * l + 3];
        const float* W_iu = (const float*)d_in[12 + 6 * l + 4];
        const float* b_iu = (const float*)d_in[12 + 6 * l + 5];
        const int relu = (l < 2) ? 1 : 0;

        // aggregate-first: m[d] = sum over in-edges of x[src]*rsqrt(deg_out[src])
        gather_scaled<<<gat_blocks_u, 256, 0, stream>>>(hu, rs_out_uu, rp_uu, ei_uu, m_uu, NU);
        gather_scaled<<<gat_blocks_i, 256, 0, stream>>>(hu, rs_out_ui, rp_ui, ei_ui, m_ui, NI);
        gather_scaled<<<gat_blocks_u, 256, 0, stream>>>(hi, rs_out_iu, rp_iu, ei_iu, m_iu, NU);
        // GEMM with fused epilogue: relu((m @ W) * rsqrt(deg_in) + b), summed per dst ntype
        gemm128<<<(NU + 63) / 64, 256, 0, stream>>>(m_uu, HD, NU, W_uu, b_uu, rs_in_uu, relu, 0, hu);
        gemm128<<<(NU + 63) / 64, 256, 0, stream>>>(m_iu, HD, NU, W_iu, b_iu, rs_in_iu, relu, 1, hu);
        gemm128<<<(NI + 63) / 64, 256, 0, stream>>>(m_ui, HD, NI, W_ui, b_ui, rs_in_ui, relu, 0, hi);
    }
}